// Round 13
// baseline (162.294 us; speedup 1.0000x reference)
//
#include <hip/hip_runtime.h>

// ---------------- problem constants ----------------
#define CC   5
#define MHW  512
#define NIM  2048
#define R_LO 488
#define NRM  1088
#define NCM  576

#define PSM  41
#define NPM  192
#define PR_LO 40
#define PNR  112
#define PNC  56

#define PSO  61
#define NPO  256
#define NCO  129

#define TT   257
#define KXN  129
#define OBS  220

#define DPI 3.14159265358979323846264338327950288
#define PIF 3.14159265358979f

static __device__ __forceinline__ float2 cmulf2(float2 a, float2 b) {
    return make_float2(a.x * b.x - a.y * b.y, a.x * b.y + a.y * b.x);
}

// ================= stage 1: row FFT (single-wave blocks) =================
// T1r[m][c] = sum_x model[m][x] e^{-2pi i c x/2048}, c in [0,576), m = ch*512+y.
// c = 4u+v: F(4u+v) = DFT_512(x[t] * e^{-2pi i v t/2048})[u], keep u < 144.
// 64 threads = 1 wave: __syncthreads() lowers to lgkmcnt waits only (no s_barrier),
// eliminating the 44 inter-wave barriers/block of the 256-thread version.
__global__ __launch_bounds__(64) void fft_row(const float* __restrict__ A,
                                              float2* __restrict__ T1r) {
    __shared__ float2 Ab[512];
    __shared__ float2 Bb[512];
    __shared__ float2 tw[256];     // tw[t] = exp(-2pi i t/512)
    __shared__ float2 outw[NCM];
    int tid = threadIdx.x;
    int row = blockIdx.x;          // ch*512 + y
    for (int t = tid; t < 256; t += 64) {
        float th = (float)t * (-2.0f * PIF / 512.0f);
        float s, c; __sincosf(th, &s, &c);
        tw[t] = make_float2(c, s);
    }
    float r[8];
    #pragma unroll
    for (int j = 0; j < 8; j++) r[j] = A[(size_t)row * 512 + tid + j * 64];
    __syncthreads();
    for (int v = 0; v < 4; v++) {
        #pragma unroll
        for (int j = 0; j < 8; j++) {
            int t = tid + j * 64;
            float th = (float)(v * t) * (-2.0f * PIF / 2048.0f);
            float s, c; __sincosf(th, &s, &c);
            Ab[t] = make_float2(r[j] * c, r[j] * s);
        }
        __syncthreads();
        float2 *src = Ab, *dst = Bb;
        #pragma unroll
        for (int s = 0; s < 9; s++) {
            int Ns = 1 << s;
            #pragma unroll
            for (int b = 0; b < 4; b++) {
                int t = tid + b * 64;
                int jm = t & (Ns - 1);
                float2 v0 = src[t];
                float2 v1 = cmulf2(tw[jm << (8 - s)], src[t + 256]);
                int idxD = ((t >> s) << (s + 1)) + jm;
                dst[idxD]      = make_float2(v0.x + v1.x, v0.y + v1.y);
                dst[idxD + Ns] = make_float2(v0.x - v1.x, v0.y - v1.y);
            }
            float2* tsw = src; src = dst; dst = tsw;
            __syncthreads();
        }
        #pragma unroll
        for (int b = 0; b < 4; b++) {
            int u = tid + b * 64;
            if (u < 144) outw[4 * u + v] = src[u];
        }
        __syncthreads();
    }
    for (int c = tid; c < NCM; c += 64)
        T1r[(size_t)row * NCM + c] = outw[c];
}

// ================= stage 2: column FFT (single-wave blocks) =================
// For (ch,n): F(k) = sum_y T1r[(ch*512+y)][n] e^{-2pi i k y/2048}, k = m-536.
__global__ __launch_bounds__(64) void fft_col(const float2* __restrict__ T1r,
                                              float2* __restrict__ Fmt) {
    __shared__ float2 Ab[512];
    __shared__ float2 Bb[512];
    __shared__ float2 tw[256];
    __shared__ float2 outw[1088];
    int tid = threadIdx.x;
    int col = blockIdx.x;          // ch*576 + n
    int ch = col / NCM, n = col - ch * NCM;
    for (int t = tid; t < 256; t += 64) {
        float th = (float)t * (-2.0f * PIF / 512.0f);
        float s, c; __sincosf(th, &s, &c);
        tw[t] = make_float2(c, s);
    }
    float2 x[8];
    #pragma unroll
    for (int j = 0; j < 8; j++)
        x[j] = T1r[((size_t)ch * 512 + tid + j * 64) * NCM + n];
    __syncthreads();
    for (int v = 0; v < 4; v++) {
        #pragma unroll
        for (int j = 0; j < 8; j++) {
            int t = tid + j * 64;
            float th = (float)(v * t) * (-2.0f * PIF / 2048.0f);
            float s, c; __sincosf(th, &s, &c);
            Ab[t] = cmulf2(make_float2(c, s), x[j]);
        }
        __syncthreads();
        float2 *src = Ab, *dst = Bb;
        #pragma unroll
        for (int s = 0; s < 9; s++) {
            int Ns = 1 << s;
            #pragma unroll
            for (int b = 0; b < 4; b++) {
                int t = tid + b * 64;
                int jm = t & (Ns - 1);
                float2 v0 = src[t];
                float2 v1 = cmulf2(tw[jm << (8 - s)], src[t + 256]);
                int idxD = ((t >> s) << (s + 1)) + jm;
                dst[idxD]      = make_float2(v0.x + v1.x, v0.y + v1.y);
                dst[idxD + Ns] = make_float2(v0.x - v1.x, v0.y - v1.y);
            }
            float2* tsw = src; src = dst; dst = tsw;
            __syncthreads();
        }
        // window k in [-536,552) -> m = k+536 (F is 2048-periodic)
        #pragma unroll
        for (int b = 0; b < 8; b++) {
            int u = tid + b * 64;
            int kr = 4 * u + v;
            if (kr <= 551)       outw[kr + 536]  = src[u];
            else if (kr >= 1512) outw[kr - 1512] = src[u];
        }
        __syncthreads();
    }
    for (int m = tid; m < 1088; m += 64)
        Fmt[(size_t)col * 1088 + m] = outw[m];
}

// ================= fused psf stage 1 (psf_model x-DFT + psf_obs x-DFT) ======
#define M1B 45    // ceil(5*41*56/256)
#define O1B 154   // ceil(5*61*129/256)
__global__ __launch_bounds__(256) void psf_s1(const float* __restrict__ psfm,
                                              const float* __restrict__ psfo,
                                              float2* __restrict__ Tp,
                                              float2* __restrict__ To) {
    __shared__ float2 t192s[NPM];
    __shared__ float2 t256s[NPO];
    int tid = threadIdx.x;
    for (int t = tid; t < NPM; t += 256) {
        double a = -2.0 * DPI * (double)t / (double)NPM;
        t192s[t] = make_float2((float)cos(a), (float)sin(a));
    }
    {
        double a = -2.0 * DPI * (double)tid / (double)NPO;
        t256s[tid] = make_float2((float)cos(a), (float)sin(a));
    }
    __syncthreads();
    int b = blockIdx.x;
    if (b < M1B) {
        int idx = b * 256 + tid;
        if (idx >= CC * PSM * PNC) return;
        int c = idx % PNC, y = (idx / PNC) % PSM, ch = idx / (PNC * PSM);
        const float* p = psfm + (ch * PSM + y) * PSM;
        float2 acc = make_float2(0.f, 0.f);
        for (int x = 0; x < PSM; x++) {
            float2 w = t192s[(c * x) % NPM];
            float v = p[x];
            acc.x = fmaf(v, w.x, acc.x);
            acc.y = fmaf(v, w.y, acc.y);
        }
        Tp[idx] = acc;
    } else {
        int idx = (b - M1B) * 256 + tid;
        if (idx >= CC * PSO * NCO) return;
        int c = idx % NCO, y = (idx / NCO) % PSO, ch = idx / (NCO * PSO);
        const float* p = psfo + (ch * PSO + y) * PSO;
        float2 acc = make_float2(0.f, 0.f);
        for (int x = 0; x < PSO; x++) {
            float2 w = t256s[(c * x) & (NPO - 1)];
            float v = p[x];
            acc.x = fmaf(v, w.x, acc.x);
            acc.y = fmaf(v, w.y, acc.y);
        }
        To[idx] = acc;
    }
}

// ================= fused psf stage 2 (y-DFTs) =================
#define M2B 123   // ceil(5*112*56/256)
#define O2B 645   // ceil(5*256*129/256)
__global__ __launch_bounds__(256) void psf_s2(const float2* __restrict__ Tp,
                                              const float2* __restrict__ To,
                                              float2* __restrict__ Fp,
                                              float2* __restrict__ Fo) {
    __shared__ float2 t192s[NPM];
    __shared__ float2 t256s[NPO];
    int tid = threadIdx.x;
    for (int t = tid; t < NPM; t += 256) {
        double a = -2.0 * DPI * (double)t / (double)NPM;
        t192s[t] = make_float2((float)cos(a), (float)sin(a));
    }
    {
        double a = -2.0 * DPI * (double)tid / (double)NPO;
        t256s[tid] = make_float2((float)cos(a), (float)sin(a));
    }
    __syncthreads();
    int b = blockIdx.x;
    if (b < M2B) {
        int idx = b * 256 + tid;
        if (idx >= CC * PNR * PNC) return;
        int c = idx % PNC, rr = (idx / PNC) % PNR, ch = idx / (PNC * PNR);
        int ky = rr + (PR_LO - 96);
        const float2* t = Tp + (ch * PSM) * PNC + c;
        float2 acc = make_float2(0.f, 0.f);
        for (int y = 0; y < PSM; y++) {
            int tt = (ky * y) % NPM; if (tt < 0) tt += NPM;
            float2 w = t192s[tt];
            float2 v = t[y * PNC];
            acc.x = fmaf(v.x, w.x, acc.x); acc.x = fmaf(-v.y, w.y, acc.x);
            acc.y = fmaf(v.x, w.y, acc.y); acc.y = fmaf(v.y, w.x, acc.y);
        }
        Fp[idx] = acc;
    } else {
        int idx = (b - M2B) * 256 + tid;
        if (idx >= CC * NPO * NCO) return;
        int c = idx % NCO, r = (idx / NCO) % NPO, ch = idx / (NCO * NPO);
        int ky = r - 128;
        const float2* t = To + (ch * PSO) * NCO + c;
        float2 acc = make_float2(0.f, 0.f);
        for (int y = 0; y < PSO; y++) {
            float2 w = t256s[(ky * y) & (NPO - 1)];
            float2 v = t[y * NCO];
            acc.x = fmaf(v.x, w.x, acc.x); acc.x = fmaf(-v.y, w.y, acc.x);
            acc.y = fmaf(v.x, w.y, acc.y); acc.y = fmaf(v.y, w.x, acc.y);
        }
        Fo[idx] = acc;
    }
}

// ================= resample + combine =================
__global__ __launch_bounds__(256) void sampler(const float2* __restrict__ Fmt,
                                               const float2* __restrict__ Fp,
                                               const float2* __restrict__ Fo,
                                               float2* __restrict__ KF) {
    __shared__ float2 t8[8];
    __shared__ float2 t192[NPM];
    __shared__ float2 t256[NPO];
    int tid = threadIdx.x;
    if (tid < 8) {
        double a = 2.0 * DPI * (double)tid / 8.0;
        t8[tid] = make_float2((float)cos(a), (float)sin(a));
    }
    for (int t = tid; t < NPM; t += 256) {
        double a = 2.0 * DPI * (double)t / (double)NPM;
        t192[t] = make_float2((float)cos(a), (float)sin(a));
    }
    {
        double a = 2.0 * DPI * (double)tid / (double)NPO;
        t256[tid] = make_float2((float)cos(a), (float)sin(a));
    }
    __syncthreads();
    int idx = blockIdx.x * 256 + tid;
    if (idx >= CC * TT * KXN) return;
    int j = idx % KXN, i = (idx / KXN) % TT, ch = idx / (KXN * TT);

    float fkx = (float)j;
    float fky = (float)(i - 129);

    const float CS  = (float)0.9987502603949669;   // cos(0.05)
    const float SN  = (float)0.04997916927067832;  // sin(0.05)
    const float SCM = (float)(2048.0 * 0.2 / (257.0 * 0.4));
    const float SCP = (float)(192.0  * 0.2 / (257.0 * 0.4));
    const float SCO = (float)(256.0  * 0.4 / (257.0 * 0.4));

    // ---- model image (Fmt is [ch][n][m]) ----
    float2 vm;
    {
        float fx = fkx * SCM, fy = fky * SCM;
        float fxr = CS * fx - SN * fy;
        float fyr = SN * fx + CS * fy;
        bool neg = fxr < 0.0f;
        float fxs = neg ? -fxr : fxr;
        float fys = neg ? -fyr : fyr;
        float rows = fys + 1024.0f, cols = fxs;
        float r0f = floorf(rows), c0f = floorf(cols);
        int r0 = (int)r0f, c0 = (int)c0f;
        float dr = rows - r0f, dc = cols - c0f;
        float2 g[2][2];
        #pragma unroll
        for (int a = 0; a < 2; a++)
            #pragma unroll
            for (int b = 0; b < 2; b++) {
                int r = r0 + a, c = c0 + b;
                float2 v = make_float2(0.f, 0.f);
                if (r >= R_LO && r < R_LO + NRM && c >= 0 && c < NCM) {
                    float2 f = Fmt[((size_t)ch * NCM + c) * NRM + (r - R_LO)];
                    v = cmulf2(t8[(r - 1024 + c) & 7], f);
                }
                g[a][b] = v;
            }
        float w00 = (1.f - dr) * (1.f - dc), w10 = dr * (1.f - dc);
        float w01 = (1.f - dr) * dc,         w11 = dr * dc;
        vm.x = g[0][0].x * w00 + g[1][0].x * w10 + g[0][1].x * w01 + g[1][1].x * w11;
        vm.y = g[0][0].y * w00 + g[1][0].y * w10 + g[0][1].y * w01 + g[1][1].y * w11;
        if (neg) vm.y = -vm.y;
    }

    // ---- model psf ----
    float2 vp;
    {
        float fx = fkx * SCP, fy = fky * SCP;
        float fxr = CS * fx - SN * fy;
        float fyr = SN * fx + CS * fy;
        bool neg = fxr < 0.0f;
        float fxs = neg ? -fxr : fxr;
        float fys = neg ? -fyr : fyr;
        float rows = fys + 96.0f, cols = fxs;
        float r0f = floorf(rows), c0f = floorf(cols);
        int r0 = (int)r0f, c0 = (int)c0f;
        float dr = rows - r0f, dc = cols - c0f;
        float2 g[2][2];
        #pragma unroll
        for (int a = 0; a < 2; a++)
            #pragma unroll
            for (int b = 0; b < 2; b++) {
                int r = r0 + a, c = c0 + b;
                float2 v = make_float2(0.f, 0.f);
                if (r >= PR_LO && r < PR_LO + PNR && c >= 0 && c < PNC) {
                    float2 f = Fp[((size_t)ch * PNR + (r - PR_LO)) * PNC + c];
                    int k = r - 96 + c;
                    int tph = (21 * k) % NPM; if (tph < 0) tph += NPM;
                    v = cmulf2(t192[tph], f);
                }
                g[a][b] = v;
            }
        float w00 = (1.f - dr) * (1.f - dc), w10 = dr * (1.f - dc);
        float w01 = (1.f - dr) * dc,         w11 = dr * dc;
        vp.x = g[0][0].x * w00 + g[1][0].x * w10 + g[0][1].x * w01 + g[1][1].x * w11;
        vp.y = g[0][0].y * w00 + g[1][0].y * w10 + g[0][1].y * w01 + g[1][1].y * w11;
        if (neg) vp.y = -vp.y;
    }

    // ---- obs psf ----
    float2 vo;
    {
        float fx = fkx * SCO, fy = fky * SCO;
        float rows = fy + 128.0f, cols = fx;
        float r0f = floorf(rows), c0f = floorf(cols);
        int r0 = (int)r0f, c0 = (int)c0f;
        float dr = rows - r0f, dc = cols - c0f;
        float2 g[2][2];
        #pragma unroll
        for (int a = 0; a < 2; a++)
            #pragma unroll
            for (int b = 0; b < 2; b++) {
                int r = r0 + a, c = c0 + b;
                float2 v = make_float2(0.f, 0.f);
                if (r >= 0 && r < NPO && c >= 0 && c < NCO) {
                    float2 f = Fo[((size_t)ch * NPO + r) * NCO + c];
                    int tph = (31 * (r - 128 + c)) & (NPO - 1);
                    v = cmulf2(t256[tph], f);
                }
                g[a][b] = v;
            }
        float w00 = (1.f - dr) * (1.f - dc), w10 = dr * (1.f - dc);
        float w01 = (1.f - dr) * dc,         w11 = dr * dc;
        vo.x = g[0][0].x * w00 + g[1][0].x * w10 + g[0][1].x * w01 + g[1][1].x * w11;
        vo.y = g[0][0].y * w00 + g[1][0].y * w10 + g[0][1].y * w01 + g[1][1].y * w11;
    }

    float den = vp.x * vp.x + vp.y * vp.y;
    float2 q = make_float2((vm.x * vp.x + vm.y * vp.y) / den,
                           (vm.y * vp.x - vm.x * vp.y) / den);
    KF[idx] = cmulf2(q, vo);
}

// ================= fused inverse (row DFT + col cosine sum), ILP version ====
#define SWZ(t) ((t) ^ (((t) >> 4) & 15))
__global__ __launch_bounds__(512) void inv12(const float2* __restrict__ KF,
                                             float* __restrict__ out) {
    __shared__ float2 t256[NPO];
    __shared__ float2 part[4][128];
    __shared__ float2 arow[128];
    int tid = threadIdx.x;
    if (tid < NPO) {
        double a = 2.0 * DPI * (double)tid / (double)NPO;
        t256[SWZ(tid)] = make_float2((float)cos(a), (float)sin(a));
    }
    __syncthreads();
    int mr = blockIdx.x, ch = blockIdx.y;
    int mp = 146 + mr;   // (18+mr) + 128 folds ifftshift row offset
    int kx = tid & 127, q = tid >> 7;
    const float2* base = KF + (size_t)ch * TT * KXN + kx;
    float2 a0 = make_float2(0.f, 0.f), a1 = a0, a2 = a0, a3 = a0;
    int rlo = q * 64;
    #pragma unroll 4
    for (int rr = 0; rr < 64; rr += 4) {
        int r = rlo + rr;
        float2 k0 = base[(size_t)(r + 0) * KXN];
        float2 k1 = base[(size_t)(r + 1) * KXN];
        float2 k2 = base[(size_t)(r + 2) * KXN];
        float2 k3 = base[(size_t)(r + 3) * KXN];
        int i0 = ((r + 0) * mp) & 255;
        int i1 = ((r + 1) * mp) & 255;
        int i2 = ((r + 2) * mp) & 255;
        int i3 = ((r + 3) * mp) & 255;
        float2 w0 = t256[SWZ(i0)], w1 = t256[SWZ(i1)];
        float2 w2 = t256[SWZ(i2)], w3 = t256[SWZ(i3)];
        a0.x = fmaf(k0.x, w0.x, a0.x); a0.x = fmaf(-k0.y, w0.y, a0.x);
        a0.y = fmaf(k0.x, w0.y, a0.y); a0.y = fmaf(k0.y, w0.x, a0.y);
        a1.x = fmaf(k1.x, w1.x, a1.x); a1.x = fmaf(-k1.y, w1.y, a1.x);
        a1.y = fmaf(k1.x, w1.y, a1.y); a1.y = fmaf(k1.y, w1.x, a1.y);
        a2.x = fmaf(k2.x, w2.x, a2.x); a2.x = fmaf(-k2.y, w2.y, a2.x);
        a2.y = fmaf(k2.x, w2.y, a2.y); a2.y = fmaf(k2.y, w2.x, a2.y);
        a3.x = fmaf(k3.x, w3.x, a3.x); a3.x = fmaf(-k3.y, w3.y, a3.x);
        a3.y = fmaf(k3.x, w3.y, a3.y); a3.y = fmaf(k3.y, w3.x, a3.y);
    }
    if (q == 0) {   // fold row 256 onto r=0 (twiddle at r=0 is 1)
        float2 fold = base[(size_t)256 * KXN];
        a0.x += fold.x; a0.y += fold.y;
    }
    part[q][kx] = make_float2((a0.x + a1.x) + (a2.x + a3.x),
                              (a0.y + a1.y) + (a2.y + a3.y));
    __syncthreads();
    if (tid < 128) {
        float2 p0 = part[0][tid], p1 = part[1][tid];
        float2 p2 = part[2][tid], p3 = part[3][tid];
        arow[tid] = make_float2((p0.x + p1.x) + (p2.x + p3.x),
                                (p0.y + p1.y) + (p2.y + p3.y));
    }
    __syncthreads();
    if (tid >= OBS) return;
    int np = 146 + tid;  // (18+tid) + 128 folds ifftshift col offset
    float s0 = 0.f, s1 = 0.f, s2 = 0.f, s3 = 0.f;
    #pragma unroll 4
    for (int k = 1; k + 3 <= 127; k += 4) {
        float2 v0 = arow[k + 0], v1 = arow[k + 1];
        float2 v2 = arow[k + 2], v3 = arow[k + 3];
        int i0 = ((k + 0) * np) & 255;
        int i1 = ((k + 1) * np) & 255;
        int i2 = ((k + 2) * np) & 255;
        int i3 = ((k + 3) * np) & 255;
        float2 w0 = t256[SWZ(i0)], w1 = t256[SWZ(i1)];
        float2 w2 = t256[SWZ(i2)], w3 = t256[SWZ(i3)];
        s0 = fmaf(v0.x, w0.x, s0); s0 = fmaf(-v0.y, w0.y, s0);
        s1 = fmaf(v1.x, w1.x, s1); s1 = fmaf(-v1.y, w1.y, s1);
        s2 = fmaf(v2.x, w2.x, s2); s2 = fmaf(-v2.y, w2.y, s2);
        s3 = fmaf(v3.x, w3.x, s3); s3 = fmaf(-v3.y, w3.y, s3);
    }
    for (int k = 125; k < 128; k++) {   // tail
        float2 v = arow[k];
        int i = (k * np) & 255;
        float2 w = t256[SWZ(i)];
        s0 = fmaf(v.x, w.x, s0); s0 = fmaf(-v.y, w.y, s0);
    }
    float s = arow[0].x + 2.0f * ((s0 + s1) + (s2 + s3));
    s *= (1.0f / 65536.0f);
    if (mr & 1) s = -s;
    out[((size_t)ch * OBS + mr) * OBS + tid] = s;
}

// ---------------- launch ----------------
extern "C" void kernel_launch(void* const* d_in, const int* in_sizes, int n_in,
                              void* d_out, int out_size, void* d_ws, size_t ws_size,
                              hipStream_t stream) {
    const float* model = (const float*)d_in[0];
    const float* psfm  = (const float*)d_in[1];
    const float* psfo  = (const float*)d_in[2];
    float* out = (float*)d_out;

    float2* ws = (float2*)d_ws;
    size_t off = 0;
    float2* T1r = ws + off; off += (size_t)CC * MHW * NCM;   // [m][c] row-major
    float2* Fmt = ws + off; off += (size_t)CC * NCM * NRM;   // [ch][n][m]
    float2* Tp  = ws + off; off += (size_t)CC * PSM * PNC;
    float2* Fp  = ws + off; off += (size_t)CC * PNR * PNC;
    float2* To  = ws + off; off += (size_t)CC * PSO * NCO;
    float2* Fo  = ws + off; off += (size_t)CC * NPO * NCO;
    float2* KF  = ws + off; off += (size_t)CC * TT * KXN;
    // total ~5.1M float2 = 41 MB

    fft_row<<<CC * MHW, 64, 0, stream>>>(model, T1r);
    fft_col<<<CC * NCM, 64, 0, stream>>>(T1r, Fmt);

    psf_s1<<<M1B + O1B, 256, 0, stream>>>(psfm, psfo, Tp, To);
    psf_s2<<<M2B + O2B, 256, 0, stream>>>(Tp, To, Fp, Fo);

    sampler<<<(CC * TT * KXN + 255) / 256, 256, 0, stream>>>(Fmt, Fp, Fo, KF);

    inv12<<<dim3(OBS, CC), 512, 0, stream>>>(KF, out);
}

// Round 14
// 135.912 us; speedup vs baseline: 1.1941x; 1.1941x over previous
//
#include <hip/hip_runtime.h>

// ---------------- problem constants ----------------
#define CC   5
#define MHW  512
#define NIM  2048
#define R_LO 488
#define NRM  1088
#define NCM  576

#define PSM  41
#define NPM  192
#define PR_LO 40
#define PNR  112
#define PNC  56

#define PSO  61
#define NPO  256
#define NCO  129

#define TT   257
#define KXN  129
#define OBS  220

#define DPI 3.14159265358979323846264338327950288
#define PIF 3.14159265358979f
#define S2F 0.70710678118654752f

static __device__ __forceinline__ float2 cmulf2(float2 a, float2 b) {
    return make_float2(a.x * b.x - a.y * b.y, a.x * b.y + a.y * b.x);
}

// forward 8-point DFT in registers (W8 = e^{-2pi i/8})
static __device__ __forceinline__ void dft8(const float2 v[8], float2 y[8]) {
    float2 a0 = make_float2(v[0].x + v[4].x, v[0].y + v[4].y);
    float2 b0 = make_float2(v[0].x - v[4].x, v[0].y - v[4].y);
    float2 a1 = make_float2(v[1].x + v[5].x, v[1].y + v[5].y);
    float2 b1 = make_float2(v[1].x - v[5].x, v[1].y - v[5].y);
    float2 a2 = make_float2(v[2].x + v[6].x, v[2].y + v[6].y);
    float2 b2 = make_float2(v[2].x - v[6].x, v[2].y - v[6].y);
    float2 a3 = make_float2(v[3].x + v[7].x, v[3].y + v[7].y);
    float2 b3 = make_float2(v[3].x - v[7].x, v[3].y - v[7].y);
    // even outputs: DFT4(a)
    float2 e0 = make_float2(a0.x + a2.x, a0.y + a2.y);
    float2 e1 = make_float2(a0.x - a2.x, a0.y - a2.y);
    float2 f0 = make_float2(a1.x + a3.x, a1.y + a3.y);
    float2 f1 = make_float2(a1.x - a3.x, a1.y - a3.y);
    y[0] = make_float2(e0.x + f0.x, e0.y + f0.y);
    y[4] = make_float2(e0.x - f0.x, e0.y - f0.y);
    y[2] = make_float2(e1.x + f1.y, e1.y - f1.x);   // e1 - i f1
    y[6] = make_float2(e1.x - f1.y, e1.y + f1.x);   // e1 + i f1
    // odd outputs: c_j = W8^j b_j, then DFT4(c)
    float2 c1 = make_float2(S2F * (b1.x + b1.y), S2F * (b1.y - b1.x));  // *(1-i)/sqrt2
    float2 c2 = make_float2(b2.y, -b2.x);                               // *(-i)
    float2 c3 = make_float2(S2F * (b3.y - b3.x), -S2F * (b3.x + b3.y)); // *-(1+i)/sqrt2
    float2 g0 = make_float2(b0.x + c2.x, b0.y + c2.y);
    float2 g1 = make_float2(b0.x - c2.x, b0.y - c2.y);
    float2 h0 = make_float2(c1.x + c3.x, c1.y + c3.y);
    float2 h1 = make_float2(c1.x - c3.x, c1.y - c3.y);
    y[1] = make_float2(g0.x + h0.x, g0.y + h0.y);
    y[5] = make_float2(g0.x - h0.x, g0.y - h0.y);
    y[3] = make_float2(g1.x + h1.y, g1.y - h1.x);
    y[7] = make_float2(g1.x - h1.y, g1.y + h1.x);
}

// LDS pad: spreads stage-0 writes (lane, lane+16, lane+32, lane+48 -> banks b,b+4,b+8,b+12)
#define SPAD(n) ((n) + ((n) >> 3) + ((n) >> 6))
#define SSZ 584

// ================= stage 1: row FFT, radix-8, 4 chirps in parallel =========
// T1r[m][c] = sum_x model[m][x] e^{-2pi i c x/2048}, c in [0,576), m = ch*512+y.
// c = 4u+v: F(4u+v) = DFT_512(x[t]*e^{-2pi i v t/2048})[u], u < 144.
// wave v handles chirp v; 3 radix-8 Stockham stages (Ns=1,8,64); 4 barriers/block.
__global__ __launch_bounds__(256) void fft_row(const float* __restrict__ A,
                                               float2* __restrict__ T1r) {
    __shared__ float2 BufA[4][SSZ];
    __shared__ float2 BufB[4][SSZ];
    float2* outw = &BufA[0][0];        // 576 <= 4*584, BufA dead after stage1 reads
    float*  xs   = (float*)&BufB[0][0]; // 512 floats, BufB dead-overlap until stage1 writes
    int tid = threadIdx.x, lane = tid & 63, v = tid >> 6;
    int row = blockIdx.x;              // ch*512 + y
    xs[tid]       = A[(size_t)row * 512 + tid];
    xs[tid + 256] = A[(size_t)row * 512 + 256 + tid];
    __syncthreads();
    float2 vq[8], y[8];
    float s, c;
    // chirp: m_q = W_2048^{v*(lane+64q)} = m0 * (W_32^v)^q
    __sincosf(-2.0f * PIF * (float)(v * lane) / 2048.0f, &s, &c);
    float2 m = make_float2(c, s);
    __sincosf(-2.0f * PIF * (float)v / 32.0f, &s, &c);
    float2 wstep = make_float2(c, s);
    #pragma unroll
    for (int q = 0; q < 8; q++) {
        float xr = xs[q * 64 + lane];
        vq[q] = make_float2(xr * m.x, xr * m.y);
        m = cmulf2(m, wstep);
    }
    dft8(vq, y);                        // stage 0 (Ns=1, no twiddles)
    #pragma unroll
    for (int p = 0; p < 8; p++) BufA[v][SPAD(8 * lane + p)] = y[p];
    __syncthreads();
    // stage 1 (Ns=8): v_q *= W_64^{q*jm}
    int jm = lane & 7, g = lane >> 3;
    __sincosf(-2.0f * PIF * (float)jm / 64.0f, &s, &c);
    float2 w1 = make_float2(c, s);
    float2 wq = make_float2(1.f, 0.f);
    #pragma unroll
    for (int q = 0; q < 8; q++) {
        vq[q] = cmulf2(wq, BufA[v][SPAD(lane + q * 64)]);
        wq = cmulf2(wq, w1);
    }
    dft8(vq, y);
    #pragma unroll
    for (int p = 0; p < 8; p++) BufB[v][SPAD(g * 64 + jm + p * 8)] = y[p];
    __syncthreads();
    // stage 2 (Ns=64): v_q *= W_512^{q*lane}; output F[lane+64p] in regs
    __sincosf(-2.0f * PIF * (float)lane / 512.0f, &s, &c);
    float2 w2 = make_float2(c, s);
    wq = make_float2(1.f, 0.f);
    #pragma unroll
    for (int q = 0; q < 8; q++) {
        vq[q] = cmulf2(wq, BufB[v][SPAD(lane + q * 64)]);
        wq = cmulf2(wq, w2);
    }
    dft8(vq, y);
    // window: c = 4u+v, u < 144  (BufA free: its last reads were pre-stage1-barrier)
    #pragma unroll
    for (int p = 0; p < 8; p++) {
        int u = lane + p * 64;
        if (u < 144) outw[4 * u + v] = y[p];
    }
    __syncthreads();
    for (int cc = tid; cc < NCM; cc += 256)
        T1r[(size_t)row * NCM + cc] = outw[cc];
}

// ================= stage 2: column FFT, radix-8, 4 chirps in parallel ======
// For (ch,n): F(k) = sum_y T1r[(ch*512+y)][n] e^{-2pi i k y/2048}, k = m-536.
__global__ __launch_bounds__(256) void fft_col(const float2* __restrict__ T1r,
                                               float2* __restrict__ Fmt) {
    __shared__ float2 BufA[4][SSZ];
    __shared__ float2 BufB[4][SSZ];
    float2* outw = &BufA[0][0];        // 1088 <= 4*584
    float2* xs   = &BufB[0][0];        // 512 float2
    int tid = threadIdx.x, lane = tid & 63, v = tid >> 6;
    int col = blockIdx.x;              // ch*576 + n
    int ch = col / NCM, n = col - ch * NCM;
    xs[tid]       = T1r[((size_t)ch * 512 + tid) * NCM + n];
    xs[tid + 256] = T1r[((size_t)ch * 512 + 256 + tid) * NCM + n];
    __syncthreads();
    float2 vq[8], y[8];
    float s, c;
    __sincosf(-2.0f * PIF * (float)(v * lane) / 2048.0f, &s, &c);
    float2 m = make_float2(c, s);
    __sincosf(-2.0f * PIF * (float)v / 32.0f, &s, &c);
    float2 wstep = make_float2(c, s);
    #pragma unroll
    for (int q = 0; q < 8; q++) {
        vq[q] = cmulf2(m, xs[q * 64 + lane]);
        m = cmulf2(m, wstep);
    }
    dft8(vq, y);
    #pragma unroll
    for (int p = 0; p < 8; p++) BufA[v][SPAD(8 * lane + p)] = y[p];
    __syncthreads();
    int jm = lane & 7, g = lane >> 3;
    __sincosf(-2.0f * PIF * (float)jm / 64.0f, &s, &c);
    float2 w1 = make_float2(c, s);
    float2 wq = make_float2(1.f, 0.f);
    #pragma unroll
    for (int q = 0; q < 8; q++) {
        vq[q] = cmulf2(wq, BufA[v][SPAD(lane + q * 64)]);
        wq = cmulf2(wq, w1);
    }
    dft8(vq, y);
    #pragma unroll
    for (int p = 0; p < 8; p++) BufB[v][SPAD(g * 64 + jm + p * 8)] = y[p];
    __syncthreads();
    __sincosf(-2.0f * PIF * (float)lane / 512.0f, &s, &c);
    float2 w2 = make_float2(c, s);
    wq = make_float2(1.f, 0.f);
    #pragma unroll
    for (int q = 0; q < 8; q++) {
        vq[q] = cmulf2(wq, BufB[v][SPAD(lane + q * 64)]);
        wq = cmulf2(wq, w2);
    }
    dft8(vq, y);
    // window k in [-536,552) -> m = k+536; k = 4u+v, u = lane+64p
    #pragma unroll
    for (int p = 0; p < 8; p++) {
        int u = lane + p * 64;
        int kr = 4 * u + v;
        if (kr <= 551)       outw[kr + 536]  = y[p];
        else if (kr >= 1512) outw[kr - 1512] = y[p];
    }
    __syncthreads();
    for (int mm = tid; mm < 1088; mm += 256)
        Fmt[(size_t)col * 1088 + mm] = outw[mm];
}

// ================= fused psf stage 1 (psf_model x-DFT + psf_obs x-DFT) ======
#define M1B 45    // ceil(5*41*56/256)
#define O1B 154   // ceil(5*61*129/256)
__global__ __launch_bounds__(256) void psf_s1(const float* __restrict__ psfm,
                                              const float* __restrict__ psfo,
                                              float2* __restrict__ Tp,
                                              float2* __restrict__ To) {
    __shared__ float2 t192s[NPM];
    __shared__ float2 t256s[NPO];
    int tid = threadIdx.x;
    for (int t = tid; t < NPM; t += 256) {
        double a = -2.0 * DPI * (double)t / (double)NPM;
        t192s[t] = make_float2((float)cos(a), (float)sin(a));
    }
    {
        double a = -2.0 * DPI * (double)tid / (double)NPO;
        t256s[tid] = make_float2((float)cos(a), (float)sin(a));
    }
    __syncthreads();
    int b = blockIdx.x;
    if (b < M1B) {
        int idx = b * 256 + tid;
        if (idx >= CC * PSM * PNC) return;
        int c = idx % PNC, y = (idx / PNC) % PSM, ch = idx / (PNC * PSM);
        const float* p = psfm + (ch * PSM + y) * PSM;
        float2 acc = make_float2(0.f, 0.f);
        for (int x = 0; x < PSM; x++) {
            float2 w = t192s[(c * x) % NPM];
            float v = p[x];
            acc.x = fmaf(v, w.x, acc.x);
            acc.y = fmaf(v, w.y, acc.y);
        }
        Tp[idx] = acc;
    } else {
        int idx = (b - M1B) * 256 + tid;
        if (idx >= CC * PSO * NCO) return;
        int c = idx % NCO, y = (idx / NCO) % PSO, ch = idx / (NCO * PSO);
        const float* p = psfo + (ch * PSO + y) * PSO;
        float2 acc = make_float2(0.f, 0.f);
        for (int x = 0; x < PSO; x++) {
            float2 w = t256s[(c * x) & (NPO - 1)];
            float v = p[x];
            acc.x = fmaf(v, w.x, acc.x);
            acc.y = fmaf(v, w.y, acc.y);
        }
        To[idx] = acc;
    }
}

// ================= fused psf stage 2 (y-DFTs) =================
#define M2B 123   // ceil(5*112*56/256)
#define O2B 645   // ceil(5*256*129/256)
__global__ __launch_bounds__(256) void psf_s2(const float2* __restrict__ Tp,
                                              const float2* __restrict__ To,
                                              float2* __restrict__ Fp,
                                              float2* __restrict__ Fo) {
    __shared__ float2 t192s[NPM];
    __shared__ float2 t256s[NPO];
    int tid = threadIdx.x;
    for (int t = tid; t < NPM; t += 256) {
        double a = -2.0 * DPI * (double)t / (double)NPM;
        t192s[t] = make_float2((float)cos(a), (float)sin(a));
    }
    {
        double a = -2.0 * DPI * (double)tid / (double)NPO;
        t256s[tid] = make_float2((float)cos(a), (float)sin(a));
    }
    __syncthreads();
    int b = blockIdx.x;
    if (b < M2B) {
        int idx = b * 256 + tid;
        if (idx >= CC * PNR * PNC) return;
        int c = idx % PNC, rr = (idx / PNC) % PNR, ch = idx / (PNC * PNR);
        int ky = rr + (PR_LO - 96);
        const float2* t = Tp + (ch * PSM) * PNC + c;
        float2 acc = make_float2(0.f, 0.f);
        for (int y = 0; y < PSM; y++) {
            int tt = (ky * y) % NPM; if (tt < 0) tt += NPM;
            float2 w = t192s[tt];
            float2 v = t[y * PNC];
            acc.x = fmaf(v.x, w.x, acc.x); acc.x = fmaf(-v.y, w.y, acc.x);
            acc.y = fmaf(v.x, w.y, acc.y); acc.y = fmaf(v.y, w.x, acc.y);
        }
        Fp[idx] = acc;
    } else {
        int idx = (b - M2B) * 256 + tid;
        if (idx >= CC * NPO * NCO) return;
        int c = idx % NCO, r = (idx / NCO) % NPO, ch = idx / (NCO * NPO);
        int ky = r - 128;
        const float2* t = To + (ch * PSO) * NCO + c;
        float2 acc = make_float2(0.f, 0.f);
        for (int y = 0; y < PSO; y++) {
            float2 w = t256s[(ky * y) & (NPO - 1)];
            float2 v = t[y * NCO];
            acc.x = fmaf(v.x, w.x, acc.x); acc.x = fmaf(-v.y, w.y, acc.x);
            acc.y = fmaf(v.x, w.y, acc.y); acc.y = fmaf(v.y, w.x, acc.y);
        }
        Fo[idx] = acc;
    }
}

// ================= resample + combine =================
__global__ __launch_bounds__(256) void sampler(const float2* __restrict__ Fmt,
                                               const float2* __restrict__ Fp,
                                               const float2* __restrict__ Fo,
                                               float2* __restrict__ KF) {
    __shared__ float2 t8[8];
    __shared__ float2 t192[NPM];
    __shared__ float2 t256[NPO];
    int tid = threadIdx.x;
    if (tid < 8) {
        double a = 2.0 * DPI * (double)tid / 8.0;
        t8[tid] = make_float2((float)cos(a), (float)sin(a));
    }
    for (int t = tid; t < NPM; t += 256) {
        double a = 2.0 * DPI * (double)t / (double)NPM;
        t192[t] = make_float2((float)cos(a), (float)sin(a));
    }
    {
        double a = 2.0 * DPI * (double)tid / (double)NPO;
        t256[tid] = make_float2((float)cos(a), (float)sin(a));
    }
    __syncthreads();
    int idx = blockIdx.x * 256 + tid;
    if (idx >= CC * TT * KXN) return;
    int j = idx % KXN, i = (idx / KXN) % TT, ch = idx / (KXN * TT);

    float fkx = (float)j;
    float fky = (float)(i - 129);

    const float CS  = (float)0.9987502603949669;   // cos(0.05)
    const float SN  = (float)0.04997916927067832;  // sin(0.05)
    const float SCM = (float)(2048.0 * 0.2 / (257.0 * 0.4));
    const float SCP = (float)(192.0  * 0.2 / (257.0 * 0.4));
    const float SCO = (float)(256.0  * 0.4 / (257.0 * 0.4));

    // ---- model image (Fmt is [ch][n][m]) ----
    float2 vm;
    {
        float fx = fkx * SCM, fy = fky * SCM;
        float fxr = CS * fx - SN * fy;
        float fyr = SN * fx + CS * fy;
        bool neg = fxr < 0.0f;
        float fxs = neg ? -fxr : fxr;
        float fys = neg ? -fyr : fyr;
        float rows = fys + 1024.0f, cols = fxs;
        float r0f = floorf(rows), c0f = floorf(cols);
        int r0 = (int)r0f, c0 = (int)c0f;
        float dr = rows - r0f, dc = cols - c0f;
        float2 g[2][2];
        #pragma unroll
        for (int a = 0; a < 2; a++)
            #pragma unroll
            for (int b = 0; b < 2; b++) {
                int r = r0 + a, c = c0 + b;
                float2 v = make_float2(0.f, 0.f);
                if (r >= R_LO && r < R_LO + NRM && c >= 0 && c < NCM) {
                    float2 f = Fmt[((size_t)ch * NCM + c) * NRM + (r - R_LO)];
                    v = cmulf2(t8[(r - 1024 + c) & 7], f);
                }
                g[a][b] = v;
            }
        float w00 = (1.f - dr) * (1.f - dc), w10 = dr * (1.f - dc);
        float w01 = (1.f - dr) * dc,         w11 = dr * dc;
        vm.x = g[0][0].x * w00 + g[1][0].x * w10 + g[0][1].x * w01 + g[1][1].x * w11;
        vm.y = g[0][0].y * w00 + g[1][0].y * w10 + g[0][1].y * w01 + g[1][1].y * w11;
        if (neg) vm.y = -vm.y;
    }

    // ---- model psf ----
    float2 vp;
    {
        float fx = fkx * SCP, fy = fky * SCP;
        float fxr = CS * fx - SN * fy;
        float fyr = SN * fx + CS * fy;
        bool neg = fxr < 0.0f;
        float fxs = neg ? -fxr : fxr;
        float fys = neg ? -fyr : fyr;
        float rows = fys + 96.0f, cols = fxs;
        float r0f = floorf(rows), c0f = floorf(cols);
        int r0 = (int)r0f, c0 = (int)c0f;
        float dr = rows - r0f, dc = cols - c0f;
        float2 g[2][2];
        #pragma unroll
        for (int a = 0; a < 2; a++)
            #pragma unroll
            for (int b = 0; b < 2; b++) {
                int r = r0 + a, c = c0 + b;
                float2 v = make_float2(0.f, 0.f);
                if (r >= PR_LO && r < PR_LO + PNR && c >= 0 && c < PNC) {
                    float2 f = Fp[((size_t)ch * PNR + (r - PR_LO)) * PNC + c];
                    int k = r - 96 + c;
                    int tph = (21 * k) % NPM; if (tph < 0) tph += NPM;
                    v = cmulf2(t192[tph], f);
                }
                g[a][b] = v;
            }
        float w00 = (1.f - dr) * (1.f - dc), w10 = dr * (1.f - dc);
        float w01 = (1.f - dr) * dc,         w11 = dr * dc;
        vp.x = g[0][0].x * w00 + g[1][0].x * w10 + g[0][1].x * w01 + g[1][1].x * w11;
        vp.y = g[0][0].y * w00 + g[1][0].y * w10 + g[0][1].y * w01 + g[1][1].y * w11;
        if (neg) vp.y = -vp.y;
    }

    // ---- obs psf ----
    float2 vo;
    {
        float fx = fkx * SCO, fy = fky * SCO;
        float rows = fy + 128.0f, cols = fx;
        float r0f = floorf(rows), c0f = floorf(cols);
        int r0 = (int)r0f, c0 = (int)c0f;
        float dr = rows - r0f, dc = cols - c0f;
        float2 g[2][2];
        #pragma unroll
        for (int a = 0; a < 2; a++)
            #pragma unroll
            for (int b = 0; b < 2; b++) {
                int r = r0 + a, c = c0 + b;
                float2 v = make_float2(0.f, 0.f);
                if (r >= 0 && r < NPO && c >= 0 && c < NCO) {
                    float2 f = Fo[((size_t)ch * NPO + r) * NCO + c];
                    int tph = (31 * (r - 128 + c)) & (NPO - 1);
                    v = cmulf2(t256[tph], f);
                }
                g[a][b] = v;
            }
        float w00 = (1.f - dr) * (1.f - dc), w10 = dr * (1.f - dc);
        float w01 = (1.f - dr) * dc,         w11 = dr * dc;
        vo.x = g[0][0].x * w00 + g[1][0].x * w10 + g[0][1].x * w01 + g[1][1].x * w11;
        vo.y = g[0][0].y * w00 + g[1][0].y * w10 + g[0][1].y * w01 + g[1][1].y * w11;
    }

    float den = vp.x * vp.x + vp.y * vp.y;
    float2 q = make_float2((vm.x * vp.x + vm.y * vp.y) / den,
                           (vm.y * vp.x - vm.x * vp.y) / den);
    KF[idx] = cmulf2(q, vo);
}

// ================= fused inverse (row DFT + col cosine sum), ILP version ====
#define SWZ(t) ((t) ^ (((t) >> 4) & 15))
__global__ __launch_bounds__(512) void inv12(const float2* __restrict__ KF,
                                             float* __restrict__ out) {
    __shared__ float2 t256[NPO];
    __shared__ float2 part[4][128];
    __shared__ float2 arow[128];
    int tid = threadIdx.x;
    if (tid < NPO) {
        double a = 2.0 * DPI * (double)tid / (double)NPO;
        t256[SWZ(tid)] = make_float2((float)cos(a), (float)sin(a));
    }
    __syncthreads();
    int mr = blockIdx.x, ch = blockIdx.y;
    int mp = 146 + mr;   // (18+mr) + 128 folds ifftshift row offset
    int kx = tid & 127, q = tid >> 7;
    const float2* base = KF + (size_t)ch * TT * KXN + kx;
    float2 a0 = make_float2(0.f, 0.f), a1 = a0, a2 = a0, a3 = a0;
    int rlo = q * 64;
    #pragma unroll 4
    for (int rr = 0; rr < 64; rr += 4) {
        int r = rlo + rr;
        float2 k0 = base[(size_t)(r + 0) * KXN];
        float2 k1 = base[(size_t)(r + 1) * KXN];
        float2 k2 = base[(size_t)(r + 2) * KXN];
        float2 k3 = base[(size_t)(r + 3) * KXN];
        int i0 = ((r + 0) * mp) & 255;
        int i1 = ((r + 1) * mp) & 255;
        int i2 = ((r + 2) * mp) & 255;
        int i3 = ((r + 3) * mp) & 255;
        float2 w0 = t256[SWZ(i0)], w1 = t256[SWZ(i1)];
        float2 w2 = t256[SWZ(i2)], w3 = t256[SWZ(i3)];
        a0.x = fmaf(k0.x, w0.x, a0.x); a0.x = fmaf(-k0.y, w0.y, a0.x);
        a0.y = fmaf(k0.x, w0.y, a0.y); a0.y = fmaf(k0.y, w0.x, a0.y);
        a1.x = fmaf(k1.x, w1.x, a1.x); a1.x = fmaf(-k1.y, w1.y, a1.x);
        a1.y = fmaf(k1.x, w1.y, a1.y); a1.y = fmaf(k1.y, w1.x, a1.y);
        a2.x = fmaf(k2.x, w2.x, a2.x); a2.x = fmaf(-k2.y, w2.y, a2.x);
        a2.y = fmaf(k2.x, w2.y, a2.y); a2.y = fmaf(k2.y, w2.x, a2.y);
        a3.x = fmaf(k3.x, w3.x, a3.x); a3.x = fmaf(-k3.y, w3.y, a3.x);
        a3.y = fmaf(k3.x, w3.y, a3.y); a3.y = fmaf(k3.y, w3.x, a3.y);
    }
    if (q == 0) {   // fold row 256 onto r=0 (twiddle at r=0 is 1)
        float2 fold = base[(size_t)256 * KXN];
        a0.x += fold.x; a0.y += fold.y;
    }
    part[q][kx] = make_float2((a0.x + a1.x) + (a2.x + a3.x),
                              (a0.y + a1.y) + (a2.y + a3.y));
    __syncthreads();
    if (tid < 128) {
        float2 p0 = part[0][tid], p1 = part[1][tid];
        float2 p2 = part[2][tid], p3 = part[3][tid];
        arow[tid] = make_float2((p0.x + p1.x) + (p2.x + p3.x),
                                (p0.y + p1.y) + (p2.y + p3.y));
    }
    __syncthreads();
    if (tid >= OBS) return;
    int np = 146 + tid;  // (18+tid) + 128 folds ifftshift col offset
    float s0 = 0.f, s1 = 0.f, s2 = 0.f, s3 = 0.f;
    #pragma unroll 4
    for (int k = 1; k + 3 <= 127; k += 4) {
        float2 v0 = arow[k + 0], v1 = arow[k + 1];
        float2 v2 = arow[k + 2], v3 = arow[k + 3];
        int i0 = ((k + 0) * np) & 255;
        int i1 = ((k + 1) * np) & 255;
        int i2 = ((k + 2) * np) & 255;
        int i3 = ((k + 3) * np) & 255;
        float2 w0 = t256[SWZ(i0)], w1 = t256[SWZ(i1)];
        float2 w2 = t256[SWZ(i2)], w3 = t256[SWZ(i3)];
        s0 = fmaf(v0.x, w0.x, s0); s0 = fmaf(-v0.y, w0.y, s0);
        s1 = fmaf(v1.x, w1.x, s1); s1 = fmaf(-v1.y, w1.y, s1);
        s2 = fmaf(v2.x, w2.x, s2); s2 = fmaf(-v2.y, w2.y, s2);
        s3 = fmaf(v3.x, w3.x, s3); s3 = fmaf(-v3.y, w3.y, s3);
    }
    for (int k = 125; k < 128; k++) {   // tail
        float2 v = arow[k];
        int i = (k * np) & 255;
        float2 w = t256[SWZ(i)];
        s0 = fmaf(v.x, w.x, s0); s0 = fmaf(-v.y, w.y, s0);
    }
    float s = arow[0].x + 2.0f * ((s0 + s1) + (s2 + s3));
    s *= (1.0f / 65536.0f);
    if (mr & 1) s = -s;
    out[((size_t)ch * OBS + mr) * OBS + tid] = s;
}

// ---------------- launch ----------------
extern "C" void kernel_launch(void* const* d_in, const int* in_sizes, int n_in,
                              void* d_out, int out_size, void* d_ws, size_t ws_size,
                              hipStream_t stream) {
    const float* model = (const float*)d_in[0];
    const float* psfm  = (const float*)d_in[1];
    const float* psfo  = (const float*)d_in[2];
    float* out = (float*)d_out;

    float2* ws = (float2*)d_ws;
    size_t off = 0;
    float2* T1r = ws + off; off += (size_t)CC * MHW * NCM;   // [m][c] row-major
    float2* Fmt = ws + off; off += (size_t)CC * NCM * NRM;   // [ch][n][m]
    float2* Tp  = ws + off; off += (size_t)CC * PSM * PNC;
    float2* Fp  = ws + off; off += (size_t)CC * PNR * PNC;
    float2* To  = ws + off; off += (size_t)CC * PSO * NCO;
    float2* Fo  = ws + off; off += (size_t)CC * NPO * NCO;
    float2* KF  = ws + off; off += (size_t)CC * TT * KXN;
    // total ~5.1M float2 = 41 MB

    fft_row<<<CC * MHW, 256, 0, stream>>>(model, T1r);
    fft_col<<<CC * NCM, 256, 0, stream>>>(T1r, Fmt);

    psf_s1<<<M1B + O1B, 256, 0, stream>>>(psfm, psfo, Tp, To);
    psf_s2<<<M2B + O2B, 256, 0, stream>>>(Tp, To, Fp, Fo);

    sampler<<<(CC * TT * KXN + 255) / 256, 256, 0, stream>>>(Fmt, Fp, Fo, KF);

    inv12<<<dim3(OBS, CC), 512, 0, stream>>>(KF, out);
}